// Round 8
// baseline (234.317 us; speedup 1.0000x reference)
//
#include <hip/hip_runtime.h>
#include <hip/hip_bf16.h>

// CapsuleLayer routing, bf16 MFMA, 5 plain dispatches. B=512,P=1152,N=10,
// T=16,D=8, 3 iters. Verified 16x16x32 bf16 MFMA layouts (rounds 4-7):
//   A: m=lane&15, k=q*8+j   B: n=lane&15, k=q*8+j   D: col=lane&15, row=q*4+r
// k_sv (GEMM1+squash): s[b,nt] = sum_{p,d} x[b,pd]*(c[p,n] W[p,nt,d]), K=9216.
//   A/B fragments built on the fly from fp32 x,W (values bf16-exact); c read
//   from precomputed c[] (iter>0) or 0.1 (iter 0). 8-wave split-K + LDS
//   reduce + fused squash -> Vt bf16 / d_out fp32. grid (32,10) x 512 thr.
// k_ga (GEMM2+contraction+softmax): H[pd,nt] = sum_b x[b,pd]*Vt[nt,b] via
//   MFMA (B-frag from fp32 x on the fly — no Xt buffer), fused W-contraction
//   -> bbar update AND softmax -> c for the next iter. grid 576 x 128 thr.
// Sequence: k_sv(0), k_ga(0), k_sv(1), k_ga(1), k_sv(2). No memsets.

typedef __attribute__((ext_vector_type(8))) short bfrag;   // 8 bf16
typedef __attribute__((ext_vector_type(4))) float f32x4;

constexpr int B_ = 512, P_ = 1152, N_ = 10, NT_ = 160;
constexpr int K1_ = P_ * 8;        // 9216
constexpr int NKC_ = K1_ / 32;     // 288 k-chunks

__device__ __forceinline__ unsigned short f2bf(float f) {
    unsigned u = __float_as_uint(f);
    return (unsigned short)((u + 0x7fffu + ((u >> 16) & 1u)) >> 16);  // RNE
}

__device__ __forceinline__ bfrag mkfrag(f32x4 a, f32x4 b, float c) {
    bfrag f;
    f[0] = (short)f2bf(a.x * c); f[1] = (short)f2bf(a.y * c);
    f[2] = (short)f2bf(a.z * c); f[3] = (short)f2bf(a.w * c);
    f[4] = (short)f2bf(b.x * c); f[5] = (short)f2bf(b.y * c);
    f[6] = (short)f2bf(b.z * c); f[7] = (short)f2bf(b.w * c);
    return f;
}

// ---- GEMM1 + squash. grid (32,10), 512 thr = 8 waves, 36 K-chunks/wave ----
// mode 0: c = 0.1 (iter 0). mode 1: read c[]. mode 2: read c[], write d_out.
__global__ __launch_bounds__(512) void k_sv(const float* __restrict__ x,
                                            const float* __restrict__ W,
                                            const float* __restrict__ cglob,
                                            unsigned short* __restrict__ Vt,
                                            float* __restrict__ outp,
                                            int mode) {
    __shared__ float csh[P_];
    __shared__ float red[7 * 256];
    const int tid = threadIdx.x;
    const int w = tid >> 6, lane = tid & 63, col = lane & 15, q = lane >> 4;
    const int m0 = blockIdx.x * 16;     // 16 b-rows
    const int n0 = blockIdx.y;          // one n per block

    if (mode) {
        for (int idx = tid; idx < P_; idx += 512)
            csh[idx] = cglob[(size_t)idx * N_ + n0];
        __syncthreads();
    }

    f32x4 acc = (f32x4){0.f, 0.f, 0.f, 0.f};
    const int kc0 = w * (NKC_ / 8);     // 36 chunks per wave
#pragma unroll 4
    for (int kc = kc0; kc < kc0 + NKC_ / 8; ++kc) {
        const float* xr = x + (size_t)(m0 + col) * K1_ + kc * 32 + q * 8;
        const bfrag a = mkfrag(*(const f32x4*)xr, *(const f32x4*)(xr + 4), 1.0f);
        const int p = kc * 4 + q;
        const float* wr = W + ((size_t)p * NT_ + n0 * 16 + col) * 8;
        const float cn = mode ? csh[p] : 0.1f;
        const bfrag b = mkfrag(*(const f32x4*)wr, *(const f32x4*)(wr + 4), cn);
        acc = __builtin_amdgcn_mfma_f32_16x16x32_bf16(a, b, acc, 0, 0, 0);
    }
    if (w) {
#pragma unroll
        for (int r = 0; r < 4; ++r)
            red[(w - 1) * 256 + r * 64 + q * 16 + col] = acc[r];
    }
    __syncthreads();
    if (w == 0) {
#pragma unroll
        for (int r = 0; r < 4; ++r) {
            const int li = r * 64 + q * 16 + col;
            float s = acc[r];
#pragma unroll
            for (int j = 0; j < 7; ++j) s += red[j * 256 + li];
            float sq = s * s;                      // t = col (16 lanes)
            sq += __shfl_xor(sq, 1);
            sq += __shfl_xor(sq, 2);
            sq += __shfl_xor(sq, 4);
            sq += __shfl_xor(sq, 8);
            const float norm = sqrtf(sq);
            const float scale = sq / (1.0f + sq * (norm + 1e-9f));
            const float vv = s * scale;
            const int b = m0 + q * 4 + r;
            const int nt = n0 * 16 + col;
            if (mode == 2) outp[(size_t)b * NT_ + nt] = vv;
            else           Vt[(size_t)nt * B_ + b] = f2bf(vv);
        }
    }
}

// ---- GEMM2 + W-contraction + softmax. grid 576, 128 thr = 2-wave split-K --
// H-tile D-layout: col = pd offset (16 pd = 2 p), rows = nt = mt*16+q*4+r.
// accum 0: bbar = delta, write bbar & c. accum 1: bbar += delta, write c.
__global__ __launch_bounds__(128) void k_ga(const unsigned short* __restrict__ Vt,
                                            const float* __restrict__ x,
                                            const float* __restrict__ W,
                                            float* __restrict__ bbar,
                                            float* __restrict__ cglob,
                                            int accum) {
    __shared__ float bred[64][40];
    const int tid = threadIdx.x;
    const int w = tid >> 6, lane = tid & 63, col = lane & 15, q = lane >> 4;
    const int pd0 = blockIdx.x * 16;
    const int p = (pd0 + col) >> 3, d = col & 7;

    // prefetch the 40 W scalars needed for the contraction tail
    float wreg[N_][4];
#pragma unroll
    for (int mt = 0; mt < N_; ++mt)
#pragma unroll
        for (int r = 0; r < 4; ++r)
            wreg[mt][r] = W[((size_t)p * NT_ + mt * 16 + q * 4 + r) * 8 + d];

    f32x4 acc[N_];
#pragma unroll
    for (int mt = 0; mt < N_; ++mt) acc[mt] = (f32x4){0.f, 0.f, 0.f, 0.f};

    const int kb0 = w * 8;
#pragma unroll 2
    for (int kc = kb0; kc < kb0 + 8; ++kc) {
        // B-frag from fp32 x on the fly: B[col][k=q*8+j] = x[kc*32+q*8+j][pd0+col]
        const float* xc = x + (size_t)(kc * 32 + q * 8) * K1_ + pd0 + col;
        bfrag bf;
#pragma unroll
        for (int j = 0; j < 8; ++j) bf[j] = (short)f2bf(xc[(size_t)j * K1_]);
#pragma unroll
        for (int mt = 0; mt < N_; ++mt) {
            const bfrag af = *(const bfrag*)(Vt + (size_t)(mt * 16 + col) * B_ + kc * 32 + q * 8);
            acc[mt] = __builtin_amdgcn_mfma_f32_16x16x32_bf16(af, bf, acc[mt], 0, 0, 0);
        }
    }
    if (w) {
#pragma unroll
        for (int mt = 0; mt < N_; ++mt)
#pragma unroll
            for (int r = 0; r < 4; ++r)
                bred[lane][mt * 4 + r] = acc[mt][r];
    }
    __syncthreads();
    if (w == 0) {
        float part[N_];
#pragma unroll
        for (int mt = 0; mt < N_; ++mt) {
            float s = 0.f;
#pragma unroll
            for (int r = 0; r < 4; ++r) {
                const float h = acc[mt][r] + bred[lane][mt * 4 + r];
                s = fmaf(wreg[mt][r], h, s);
            }
            s += __shfl_xor(s, 1);    // reduce over d
            s += __shfl_xor(s, 2);
            s += __shfl_xor(s, 4);
            s += __shfl_xor(s, 16);   // reduce over t-quarters
            s += __shfl_xor(s, 32);
            part[mt] = s;
        }
        if (q == 0 && d == 0) {       // lanes 0 and 8: the 2 p's of this tile
            float bv[N_];
#pragma unroll
            for (int mt = 0; mt < N_; ++mt) {
                bv[mt] = part[mt] * (1.0f / 512.0f);
                if (accum) bv[mt] += bbar[(size_t)p * N_ + mt];
                else       bbar[(size_t)p * N_ + mt] = bv[mt];
            }
            float m = -1e30f;
#pragma unroll
            for (int mt = 0; mt < N_; ++mt) m = fmaxf(m, bv[mt]);
            float sum = 0.f;
#pragma unroll
            for (int mt = 0; mt < N_; ++mt) { bv[mt] = __expf(bv[mt] - m); sum += bv[mt]; }
            const float inv = 1.f / sum;
#pragma unroll
            for (int mt = 0; mt < N_; ++mt)
                cglob[(size_t)p * N_ + mt] = bv[mt] * inv;
        }
    }
}

extern "C" void kernel_launch(void* const* d_in, const int* in_sizes, int n_in,
                              void* d_out, int out_size, void* d_ws, size_t ws_size,
                              hipStream_t stream) {
    const float* x = (const float*)d_in[0];   // fp32 [B][P*D]
    const float* W = (const float*)d_in[1];   // fp32 [P][NT][D]

    char* wsp = (char*)d_ws;
    float* bbar = (float*)wsp;                                  // 46080 B
    float* c    = bbar + (size_t)P_ * N_;                       // 46080 B
    unsigned short* Vt = (unsigned short*)(c + (size_t)P_ * N_); // 160 KB
    float* outp = (float*)d_out;

    k_sv<<<dim3(32, 10), dim3(512), 0, stream>>>(x, W, c, Vt, outp, 0);
    k_ga<<<dim3(576), dim3(128), 0, stream>>>(Vt, x, W, bbar, c, 0);
    k_sv<<<dim3(32, 10), dim3(512), 0, stream>>>(x, W, c, Vt, outp, 1);
    k_ga<<<dim3(576), dim3(128), 0, stream>>>(Vt, x, W, bbar, c, 1);
    k_sv<<<dim3(32, 10), dim3(512), 0, stream>>>(x, W, c, Vt, outp, 2);
}

// Round 9
// 161.496 us; speedup vs baseline: 1.4509x; 1.4509x over previous
//
#include <hip/hip_runtime.h>
#include <hip/hip_bf16.h>

// CapsuleLayer routing, bf16 MFMA, 6 dispatches, fragment-layout buffers.
// B=512,P=1152,N=10,T=16,D=8, 3 iters. Verified 16x16x32 bf16 layouts:
//   A: m=lane&15, k=q*8+j   B: n=lane&15, k=q*8+j   D: col=lane&15, row=q*4+r
// k_prep: Xb (A-frag layout), Xga (GEMM2 B-frag layout, LDS transpose),
//         Wc0 = bf16(0.1*W) (B-frag layout). One dispatch, 3 block ranges.
// k_sv:   s[b,nt]=sum_k Xb*Wc, pure load+MFMA inner loop, 8-wave split-K,
//         LDS reduce + fused squash -> Vt bf16 / d_out fp32.
// k_ga:   H[pd,nt]=sum_b Xga*Vt, fused W-contraction -> bbar update,
//         softmax -> c, and writes next iter's Wc rows for its 2 p's.

typedef __attribute__((ext_vector_type(8))) short bfrag;   // 8 bf16
typedef __attribute__((ext_vector_type(4))) float f32x4;

constexpr int B_ = 512, P_ = 1152, N_ = 10, NT_ = 160;
constexpr int K1_ = P_ * 8;        // 9216
constexpr int NKC_ = K1_ / 32;     // 288 k-chunks

__device__ __forceinline__ unsigned short f2bf(float f) {
    unsigned u = __float_as_uint(f);
    return (unsigned short)((u + 0x7fffu + ((u >> 16) & 1u)) >> 16);  // RNE
}

__device__ __forceinline__ bfrag mkfrag(f32x4 a, f32x4 b, float c) {
    bfrag f;
    f[0] = (short)f2bf(a.x * c); f[1] = (short)f2bf(a.y * c);
    f[2] = (short)f2bf(a.z * c); f[3] = (short)f2bf(a.w * c);
    f[4] = (short)f2bf(b.x * c); f[5] = (short)f2bf(b.y * c);
    f[6] = (short)f2bf(b.z * c); f[7] = (short)f2bf(b.w * c);
    return f;
}

// Xb:  [mblk 32][kc 288][lane 64][8]  elem = x[mblk*16+col][kc*32+q*8+j]
// Xga: [pdblk 576][kc 16][lane 64][8] elem = x[kc*32+q*8+j][pdblk*16+col]
// Wc:  [n 10][kc 288][lane 64][8]     elem = c[p,n]*W[p][n*16+col][j], p=kc*4+q
__global__ __launch_bounds__(256) void k_prep(const float* __restrict__ x,
                                              const float* __restrict__ W,
                                              unsigned short* __restrict__ Xb,
                                              unsigned short* __restrict__ Xga,
                                              unsigned short* __restrict__ Wc) {
    const int bid = blockIdx.x, tid = threadIdx.x;
    if (bid < 1152) {                       // LDS transpose -> Xga
        __shared__ unsigned short tile[64][72];   // [pd][b]
        const int pdt = bid >> 3, bt = bid & 7;
        const int pd0 = pdt * 64, b0 = bt * 64;
        const int c0 = tid & 63, r0 = tid >> 6;
#pragma unroll
        for (int i = 0; i < 16; ++i) {
            const int br = i * 4 + r0;
            tile[c0][br] = f2bf(x[(size_t)(b0 + br) * K1_ + pd0 + c0]);
        }
        __syncthreads();
#pragma unroll
        for (int task = tid; task < 512; task += 256) {
            const int pd_l = task >> 3, oct = task & 7;
            const int pd = pd0 + pd_l, b = b0 + oct * 8;
            bfrag f;
#pragma unroll
            for (int j = 0; j < 8; ++j) f[j] = (short)tile[pd_l][oct * 8 + j];
            const size_t addr = ((size_t)((pd >> 4) * 16 + (b >> 5))) * 512
                              + ((b >> 3) & 3) * 128 + (pd & 15) * 8;
            *(bfrag*)(Xga + addr) = f;
        }
    } else if (bid < 3456) {                // Xb A-frag layout
        const int tile_id = (bid - 1152) * 4 + (tid >> 6);
        const int lane = tid & 63, col = lane & 15, q = lane >> 4;
        const int mblk = tile_id / NKC_, kc = tile_id % NKC_;
        const float* xr = x + (size_t)(mblk * 16 + col) * K1_ + kc * 32 + q * 8;
        *(bfrag*)(Xb + (size_t)tile_id * 512 + lane * 8) =
            mkfrag(*(const f32x4*)xr, *(const f32x4*)(xr + 4), 1.0f);
    } else {                                // Wc0 = bf16(0.1*W), B-frag layout
        const int idx = (bid - 3456) * 256 + tid;   // < 184320
        const int p = idx / NT_, nt = idx % NT_, n = nt >> 4, cl = nt & 15;
        const float* wr = W + (size_t)idx * 8;
        const size_t addr = ((size_t)(n * NKC_ + (p >> 2))) * 512 + (p & 3) * 128 + cl * 8;
        *(bfrag*)(Wc + addr) = mkfrag(*(const f32x4*)wr, *(const f32x4*)(wr + 4), 0.1f);
    }
}

// ---- GEMM1 + squash. grid (32,5), 512 thr = 8 waves, 36 K-chunks/wave -----
__global__ __launch_bounds__(512) void k_sv(const unsigned short* __restrict__ Xb,
                                            const unsigned short* __restrict__ Wc,
                                            unsigned short* __restrict__ Vt,
                                            float* __restrict__ outp,
                                            int final_it) {
    __shared__ float red[7 * 512];
    const int tid = threadIdx.x;
    const int w = tid >> 6, lane = tid & 63, col = lane & 15, q = lane >> 4;
    const int mblk = blockIdx.x;        // 16 b-rows
    const int n0 = blockIdx.y * 2;      // 2 n per block

    f32x4 acc0 = (f32x4){0.f, 0.f, 0.f, 0.f};
    f32x4 acc1 = (f32x4){0.f, 0.f, 0.f, 0.f};
    const int kc0 = w * (NKC_ / 8);     // 36 chunks per wave
    const unsigned short* Xp = Xb + ((size_t)(mblk * NKC_ + kc0)) * 512 + lane * 8;
    const unsigned short* W0 = Wc + ((size_t)(n0 * NKC_ + kc0)) * 512 + lane * 8;
    const unsigned short* W1 = W0 + (size_t)NKC_ * 512;
#pragma unroll 4
    for (int i = 0; i < NKC_ / 8; ++i) {
        const bfrag a  = *(const bfrag*)Xp;
        const bfrag b0 = *(const bfrag*)W0;
        const bfrag b1 = *(const bfrag*)W1;
        acc0 = __builtin_amdgcn_mfma_f32_16x16x32_bf16(a, b0, acc0, 0, 0, 0);
        acc1 = __builtin_amdgcn_mfma_f32_16x16x32_bf16(a, b1, acc1, 0, 0, 0);
        Xp += 512; W0 += 512; W1 += 512;
    }
    if (w) {
#pragma unroll
        for (int r = 0; r < 4; ++r) {
            red[(w - 1) * 512 + r * 64 + q * 16 + col] = acc0[r];
            red[(w - 1) * 512 + 256 + r * 64 + q * 16 + col] = acc1[r];
        }
    }
    __syncthreads();
    if (w == 0) {
#pragma unroll
        for (int jn = 0; jn < 2; ++jn) {
#pragma unroll
            for (int r = 0; r < 4; ++r) {
                const int li = jn * 256 + r * 64 + q * 16 + col;
                float s = jn ? acc1[r] : acc0[r];
#pragma unroll
                for (int j = 0; j < 7; ++j) s += red[j * 512 + li];
                float sq = s * s;                      // t = col (16 lanes)
                sq += __shfl_xor(sq, 1);
                sq += __shfl_xor(sq, 2);
                sq += __shfl_xor(sq, 4);
                sq += __shfl_xor(sq, 8);
                const float norm = sqrtf(sq);
                const float scale = sq / (1.0f + sq * (norm + 1e-9f));
                const float vv = s * scale;
                const int b = mblk * 16 + q * 4 + r;
                const int nt = (n0 + jn) * 16 + col;
                if (final_it) outp[(size_t)b * NT_ + nt] = vv;
                else          Vt[(size_t)nt * B_ + b] = f2bf(vv);
            }
        }
    }
}

// ---- GEMM2 + contraction + softmax + Wc rebuild. grid 576, 256 thr --------
__global__ __launch_bounds__(256) void k_ga(const unsigned short* __restrict__ Vt,
                                            const unsigned short* __restrict__ Xga,
                                            const float* __restrict__ W,
                                            float* __restrict__ bbar,
                                            unsigned short* __restrict__ Wc,
                                            int accum) {
    __shared__ float bred[3][64][40];
    __shared__ float csm[2][N_];
    const int tid = threadIdx.x;
    const int w = tid >> 6, lane = tid & 63, col = lane & 15, q = lane >> 4;
    const int pdblk = blockIdx.x;
    const int pd0 = pdblk * 16;
    const int p = (pd0 + col) >> 3, d = col & 7;

    float wreg[N_][4];
    if (w == 0) {
#pragma unroll
        for (int mt = 0; mt < N_; ++mt)
#pragma unroll
            for (int r = 0; r < 4; ++r)
                wreg[mt][r] = W[((size_t)p * NT_ + mt * 16 + q * 4 + r) * 8 + d];
    }

    f32x4 acc[N_];
#pragma unroll
    for (int mt = 0; mt < N_; ++mt) acc[mt] = (f32x4){0.f, 0.f, 0.f, 0.f};

    const int kb0 = w * 4;
#pragma unroll
    for (int kc = kb0; kc < kb0 + 4; ++kc) {
        const bfrag bf = *(const bfrag*)(Xga + ((size_t)(pdblk * 16 + kc)) * 512 + lane * 8);
#pragma unroll
        for (int mt = 0; mt < N_; ++mt) {
            const bfrag af = *(const bfrag*)(Vt + (size_t)(mt * 16 + col) * B_ + kc * 32 + q * 8);
            acc[mt] = __builtin_amdgcn_mfma_f32_16x16x32_bf16(af, bf, acc[mt], 0, 0, 0);
        }
    }
    if (w) {
#pragma unroll
        for (int mt = 0; mt < N_; ++mt)
#pragma unroll
            for (int r = 0; r < 4; ++r)
                bred[w - 1][lane][mt * 4 + r] = acc[mt][r];
    }
    __syncthreads();
    if (w == 0) {
        float part[N_];
#pragma unroll
        for (int mt = 0; mt < N_; ++mt) {
            float s = 0.f;
#pragma unroll
            for (int r = 0; r < 4; ++r) {
                const float h = acc[mt][r] + bred[0][lane][mt * 4 + r]
                              + bred[1][lane][mt * 4 + r] + bred[2][lane][mt * 4 + r];
                s = fmaf(wreg[mt][r], h, s);
            }
            s += __shfl_xor(s, 1);    // reduce over d
            s += __shfl_xor(s, 2);
            s += __shfl_xor(s, 4);
            s += __shfl_xor(s, 16);   // reduce over t-quarters
            s += __shfl_xor(s, 32);
            part[mt] = s;
        }
        if (q == 0 && d == 0) {       // lanes 0 and 8: the block's 2 p's
            const int pl = col >> 3;
            float bv[N_];
#pragma unroll
            for (int mt = 0; mt < N_; ++mt) {
                bv[mt] = part[mt] * (1.0f / 512.0f);
                if (accum) bv[mt] += bbar[(size_t)p * N_ + mt];
                bbar[(size_t)p * N_ + mt] = bv[mt];
            }
            float m = -1e30f;
#pragma unroll
            for (int mt = 0; mt < N_; ++mt) m = fmaxf(m, bv[mt]);
            float sum = 0.f;
#pragma unroll
            for (int mt = 0; mt < N_; ++mt) { bv[mt] = __expf(bv[mt] - m); sum += bv[mt]; }
            const float inv = 1.f / sum;
#pragma unroll
            for (int mt = 0; mt < N_; ++mt) csm[pl][mt] = bv[mt] * inv;
        }
    }
    __syncthreads();
    // rebuild Wc rows for this block's 2 p's (320 rows of 8)
    const int p0 = pdblk * 2;
#pragma unroll
    for (int task = tid; task < 320; task += 256) {
        const int pl = task / 160, rem = task % 160;
        const int n = rem >> 4, cl = rem & 15;
        const int pp = p0 + pl;
        const float c = csm[pl][n];
        const float* wr = W + ((size_t)pp * NT_ + n * 16 + cl) * 8;
        const size_t addr = ((size_t)(n * NKC_ + (pp >> 2))) * 512 + (pp & 3) * 128 + cl * 8;
        *(bfrag*)(Wc + addr) = mkfrag(*(const f32x4*)wr, *(const f32x4*)(wr + 4), c);
    }
}

extern "C" void kernel_launch(void* const* d_in, const int* in_sizes, int n_in,
                              void* d_out, int out_size, void* d_ws, size_t ws_size,
                              hipStream_t stream) {
    const float* x = (const float*)d_in[0];   // fp32 [B][P*D]
    const float* W = (const float*)d_in[1];   // fp32 [P][NT][D]

    char* wsp = (char*)d_ws;
    float* bbar = (float*)wsp;                                      // 46080 B
    unsigned short* Xb  = (unsigned short*)(wsp + 46080);           // 9.44 MB
    unsigned short* Xga = Xb + (size_t)32 * NKC_ * 512;             // 9.44 MB
    unsigned short* Wc  = Xga + (size_t)576 * 16 * 512;             // 2.95 MB
    unsigned short* Vt  = Wc + (size_t)N_ * NKC_ * 512;             // 160 KB
    float* outp = (float*)d_out;

    k_prep<<<dim3(4176), dim3(256), 0, stream>>>(x, W, Xb, Xga, Wc);
    k_sv<<<dim3(32, 5), dim3(512), 0, stream>>>(Xb, Wc, Vt, outp, 0);
    k_ga<<<dim3(576), dim3(256), 0, stream>>>(Vt, Xga, W, bbar, Wc, 0);
    k_sv<<<dim3(32, 5), dim3(512), 0, stream>>>(Xb, Wc, Vt, outp, 0);
    k_ga<<<dim3(576), dim3(256), 0, stream>>>(Vt, Xga, W, bbar, Wc, 1);
    k_sv<<<dim3(32, 5), dim3(512), 0, stream>>>(Xb, Wc, Vt, outp, 1);
}

// Round 10
// 157.188 us; speedup vs baseline: 1.4907x; 1.0274x over previous
//
#include <hip/hip_runtime.h>
#include <hip/hip_bf16.h>

// CapsuleLayer routing, bf16 MFMA, 6 dispatches, fragment-layout buffers.
// B=512,P=1152,N=10,T=16,D=8, 3 iters. Verified 16x16x32 bf16 layouts:
//   A: m=lane&15, k=q*8+j   B: n=lane&15, k=q*8+j   D: col=lane&15, row=q*4+r
// k_prep: Xb (A-frag layout), Xga (GEMM2 B-frag layout, LDS transpose),
//         Wc0 = bf16(0.1*W) (B-frag layout), Wb (bf16 W in k_ga contraction
//         layout — lossless since W is bf16-exact). One dispatch, 4 ranges.
// k_sv:   s[b,nt]=sum_k Xb*Wc, pure 2-load+1-MFMA inner loop, grid (32,10)
//         single-n, 8-wave split-K + LDS reduce + fused squash.
// k_ga:   H[pd,nt]=sum_b Xga*Vt, fused W-contraction (wreg from Wb, 5x16B
//         contiguous) -> bbar update, softmax -> Wc rebuild for next iter.

typedef __attribute__((ext_vector_type(8))) short bfrag;   // 8 bf16
typedef __attribute__((ext_vector_type(4))) float f32x4;

constexpr int B_ = 512, P_ = 1152, N_ = 10, NT_ = 160;
constexpr int K1_ = P_ * 8;        // 9216
constexpr int NKC_ = K1_ / 32;     // 288 k-chunks

__device__ __forceinline__ unsigned short f2bf(float f) {
    unsigned u = __float_as_uint(f);
    return (unsigned short)((u + 0x7fffu + ((u >> 16) & 1u)) >> 16);  // RNE
}
__device__ __forceinline__ float bf2f(unsigned short s) {
    return __uint_as_float((unsigned)s << 16);
}

__device__ __forceinline__ bfrag mkfrag(f32x4 a, f32x4 b, float c) {
    bfrag f;
    f[0] = (short)f2bf(a.x * c); f[1] = (short)f2bf(a.y * c);
    f[2] = (short)f2bf(a.z * c); f[3] = (short)f2bf(a.w * c);
    f[4] = (short)f2bf(b.x * c); f[5] = (short)f2bf(b.y * c);
    f[6] = (short)f2bf(b.z * c); f[7] = (short)f2bf(b.w * c);
    return f;
}

// Xb:  [mblk 32][kc 288][lane 64][8]  elem = x[mblk*16+col][kc*32+q*8+j]
// Xga: [pdblk 576][kc 16][lane 64][8] elem = x[kc*32+q*8+j][pdblk*16+col]
// Wc:  [n 10][kc 288][lane 64][8]     elem = c[p,n]*W[p][n*16+col][j], p=kc*4+q
// Wb:  [pdblk 576][lane 64][40]       elem(mt*4+r) = W[p][mt*16+q*4+r][d]
__global__ __launch_bounds__(256) void k_prep(const float* __restrict__ x,
                                              const float* __restrict__ W,
                                              unsigned short* __restrict__ Xb,
                                              unsigned short* __restrict__ Xga,
                                              unsigned short* __restrict__ Wc,
                                              unsigned short* __restrict__ Wb) {
    const int bid = blockIdx.x, tid = threadIdx.x;
    if (bid < 1152) {                       // LDS transpose -> Xga
        __shared__ unsigned short tile[64][72];   // [pd][b], b128-aligned rows
        const int pdt = bid >> 3, bt = bid & 7;
        const int pd0 = pdt * 64, b0 = bt * 64;
        const int c0 = tid & 63, r0 = tid >> 6;
#pragma unroll
        for (int i = 0; i < 16; ++i) {
            const int br = i * 4 + r0;
            tile[c0][br] = f2bf(x[(size_t)(b0 + br) * K1_ + pd0 + c0]);
        }
        __syncthreads();
#pragma unroll
        for (int task = tid; task < 512; task += 256) {
            const int pd_l = task >> 3, oct = task & 7;
            const int pd = pd0 + pd_l, b = b0 + oct * 8;
            bfrag f;
#pragma unroll
            for (int j = 0; j < 8; ++j) f[j] = (short)tile[pd_l][oct * 8 + j];
            const size_t addr = ((size_t)((pd >> 4) * 16 + (b >> 5))) * 512
                              + ((b >> 3) & 3) * 128 + (pd & 15) * 8;
            *(bfrag*)(Xga + addr) = f;
        }
    } else if (bid < 3456) {                // Xb A-frag layout
        const int tile_id = (bid - 1152) * 4 + (tid >> 6);
        const int lane = tid & 63, col = lane & 15, q = lane >> 4;
        const int mblk = tile_id / NKC_, kc = tile_id % NKC_;
        const float* xr = x + (size_t)(mblk * 16 + col) * K1_ + kc * 32 + q * 8;
        *(bfrag*)(Xb + (size_t)tile_id * 512 + lane * 8) =
            mkfrag(*(const f32x4*)xr, *(const f32x4*)(xr + 4), 1.0f);
    } else if (bid < 4176) {                // Wc0 = bf16(0.1*W), B-frag layout
        const int idx = (bid - 3456) * 256 + tid;   // < 184320
        const int p = idx / NT_, nt = idx % NT_, n = nt >> 4, cl = nt & 15;
        const float* wr = W + (size_t)idx * 8;
        const size_t addr = ((size_t)(n * NKC_ + (p >> 2))) * 512 + (p & 3) * 128 + cl * 8;
        *(bfrag*)(Wc + addr) = mkfrag(*(const f32x4*)wr, *(const f32x4*)(wr + 4), 0.1f);
    } else {                                // Wb: contraction-layout bf16 W
        const int idx = (bid - 4176) * 256 + tid;   // < 36864
        const int pdblk = idx >> 6, lane = idx & 63;
        const int col = lane & 15, q = lane >> 4;
        const int p = (pdblk * 16 + col) >> 3, d = col & 7;
        unsigned short vals[40];
#pragma unroll
        for (int mt = 0; mt < N_; ++mt)
#pragma unroll
            for (int r = 0; r < 4; ++r)
                vals[mt * 4 + r] = f2bf(W[((size_t)p * NT_ + mt * 16 + q * 4 + r) * 8 + d]);
        unsigned short* dst = Wb + (size_t)idx * 40;
#pragma unroll
        for (int v = 0; v < 40; ++v) dst[v] = vals[v];
    }
}

// ---- GEMM1 + squash. grid (32,10), 512 thr = 8 waves, 36 K-chunks/wave ----
__global__ __launch_bounds__(512) void k_sv(const unsigned short* __restrict__ Xb,
                                            const unsigned short* __restrict__ Wc,
                                            unsigned short* __restrict__ Vt,
                                            float* __restrict__ outp,
                                            int final_it) {
    __shared__ float red[7 * 256];
    const int tid = threadIdx.x;
    const int w = tid >> 6, lane = tid & 63, col = lane & 15, q = lane >> 4;
    const int mblk = blockIdx.x;        // 16 b-rows
    const int n0 = blockIdx.y;          // one n per block

    f32x4 acc = (f32x4){0.f, 0.f, 0.f, 0.f};
    const int kc0 = w * (NKC_ / 8);     // 36 chunks per wave
    const unsigned short* Xp = Xb + ((size_t)(mblk * NKC_ + kc0)) * 512 + lane * 8;
    const unsigned short* W0 = Wc + ((size_t)(n0 * NKC_ + kc0)) * 512 + lane * 8;
#pragma unroll 6
    for (int i = 0; i < NKC_ / 8; ++i) {
        const bfrag a = *(const bfrag*)Xp;
        const bfrag b = *(const bfrag*)W0;
        acc = __builtin_amdgcn_mfma_f32_16x16x32_bf16(a, b, acc, 0, 0, 0);
        Xp += 512; W0 += 512;
    }
    if (w) {
#pragma unroll
        for (int r = 0; r < 4; ++r)
            red[(w - 1) * 256 + r * 64 + q * 16 + col] = acc[r];
    }
    __syncthreads();
    if (w == 0) {
#pragma unroll
        for (int r = 0; r < 4; ++r) {
            const int li = r * 64 + q * 16 + col;
            float s = acc[r];
#pragma unroll
            for (int j = 0; j < 7; ++j) s += red[j * 256 + li];
            float sq = s * s;                      // t = col (16 lanes)
            sq += __shfl_xor(sq, 1);
            sq += __shfl_xor(sq, 2);
            sq += __shfl_xor(sq, 4);
            sq += __shfl_xor(sq, 8);
            const float norm = sqrtf(sq);
            const float scale = sq / (1.0f + sq * (norm + 1e-9f));
            const float vv = s * scale;
            const int b = mblk * 16 + q * 4 + r;
            const int nt = n0 * 16 + col;
            if (final_it) outp[(size_t)b * NT_ + nt] = vv;
            else          Vt[(size_t)nt * B_ + b] = f2bf(vv);
        }
    }
}

// ---- GEMM2 + contraction + softmax + Wc rebuild. grid 576, 256 thr --------
__global__ __launch_bounds__(256) void k_ga(const unsigned short* __restrict__ Vt,
                                            const unsigned short* __restrict__ Xga,
                                            const unsigned short* __restrict__ Wb,
                                            const float* __restrict__ W,
                                            float* __restrict__ bbar,
                                            unsigned short* __restrict__ Wc,
                                            int accum) {
    __shared__ float bred[3][64][40];
    __shared__ float csm[2][N_];
    const int tid = threadIdx.x;
    const int w = tid >> 6, lane = tid & 63, col = lane & 15, q = lane >> 4;
    const int pdblk = blockIdx.x;
    const int p = (pdblk * 16 + col) >> 3, d = col & 7;

    f32x4 acc[N_];
#pragma unroll
    for (int mt = 0; mt < N_; ++mt) acc[mt] = (f32x4){0.f, 0.f, 0.f, 0.f};

    const int kb0 = w * 4;
#pragma unroll
    for (int kc = kb0; kc < kb0 + 4; ++kc) {
        const bfrag bf = *(const bfrag*)(Xga + ((size_t)(pdblk * 16 + kc)) * 512 + lane * 8);
#pragma unroll
        for (int mt = 0; mt < N_; ++mt) {
            const bfrag af = *(const bfrag*)(Vt + (size_t)(mt * 16 + col) * B_ + kc * 32 + q * 8);
            acc[mt] = __builtin_amdgcn_mfma_f32_16x16x32_bf16(af, bf, acc[mt], 0, 0, 0);
        }
    }
    if (w) {
#pragma unroll
        for (int mt = 0; mt < N_; ++mt)
#pragma unroll
            for (int r = 0; r < 4; ++r)
                bred[w - 1][lane][mt * 4 + r] = acc[mt][r];
    }
    __syncthreads();
    if (w == 0) {
        // contiguous 80 B of bf16 W in contraction layout
        unsigned short wv[40];
        const unsigned short* ws = Wb + ((size_t)(pdblk * 64 + lane)) * 40;
#pragma unroll
        for (int v = 0; v < 40; ++v) wv[v] = ws[v];
        float part[N_];
#pragma unroll
        for (int mt = 0; mt < N_; ++mt) {
            float s = 0.f;
#pragma unroll
            for (int r = 0; r < 4; ++r) {
                const float h = acc[mt][r] + bred[0][lane][mt * 4 + r]
                              + bred[1][lane][mt * 4 + r] + bred[2][lane][mt * 4 + r];
                s = fmaf(bf2f(wv[mt * 4 + r]), h, s);
            }
            s += __shfl_xor(s, 1);    // reduce over d
            s += __shfl_xor(s, 2);
            s += __shfl_xor(s, 4);
            s += __shfl_xor(s, 16);   // reduce over t-quarters
            s += __shfl_xor(s, 32);
            part[mt] = s;
        }
        if (q == 0 && d == 0) {       // lanes 0 and 8: the block's 2 p's
            const int pl = col >> 3;
            float bv[N_];
#pragma unroll
            for (int mt = 0; mt < N_; ++mt) {
                bv[mt] = part[mt] * (1.0f / 512.0f);
                if (accum) bv[mt] += bbar[(size_t)p * N_ + mt];
                bbar[(size_t)p * N_ + mt] = bv[mt];
            }
            float m = -1e30f;
#pragma unroll
            for (int mt = 0; mt < N_; ++mt) m = fmaxf(m, bv[mt]);
            float sum = 0.f;
#pragma unroll
            for (int mt = 0; mt < N_; ++mt) { bv[mt] = __expf(bv[mt] - m); sum += bv[mt]; }
            const float inv = 1.f / sum;
#pragma unroll
            for (int mt = 0; mt < N_; ++mt) csm[pl][mt] = bv[mt] * inv;
        }
    }
    __syncthreads();
    // rebuild Wc rows for this block's 2 p's (320 rows of 8)
    const int p0 = pdblk * 2;
#pragma unroll
    for (int task = tid; task < 320; task += 256) {
        const int pl = task / 160, rem = task % 160;
        const int n = rem >> 4, cl = rem & 15;
        const int pp = p0 + pl;
        const float c = csm[pl][n];
        const float* wr = W + ((size_t)pp * NT_ + n * 16 + cl) * 8;
        const size_t addr = ((size_t)(n * NKC_ + (pp >> 2))) * 512 + (pp & 3) * 128 + cl * 8;
        *(bfrag*)(Wc + addr) = mkfrag(*(const f32x4*)wr, *(const f32x4*)(wr + 4), c);
    }
}

extern "C" void kernel_launch(void* const* d_in, const int* in_sizes, int n_in,
                              void* d_out, int out_size, void* d_ws, size_t ws_size,
                              hipStream_t stream) {
    const float* x = (const float*)d_in[0];   // fp32 [B][P*D]
    const float* W = (const float*)d_in[1];   // fp32 [P][NT][D]

    char* wsp = (char*)d_ws;
    float* bbar = (float*)wsp;                                      // 46080 B
    unsigned short* Xb  = (unsigned short*)(wsp + 46080);           // 9.44 MB
    unsigned short* Xga = Xb + (size_t)32 * NKC_ * 512;             // 9.44 MB
    unsigned short* Wc  = Xga + (size_t)576 * 16 * 512;             // 2.95 MB
    unsigned short* Wb  = Wc + (size_t)N_ * NKC_ * 512;             // 2.95 MB
    unsigned short* Vt  = Wb + (size_t)576 * 64 * 40;               // 160 KB
    float* outp = (float*)d_out;

    k_prep<<<dim3(4320), dim3(256), 0, stream>>>(x, W, Xb, Xga, Wc, Wb);
    k_sv<<<dim3(32, 10), dim3(512), 0, stream>>>(Xb, Wc, Vt, outp, 0);
    k_ga<<<dim3(576), dim3(256), 0, stream>>>(Vt, Xga, Wb, W, bbar, Wc, 0);
    k_sv<<<dim3(32, 10), dim3(512), 0, stream>>>(Xb, Wc, Vt, outp, 0);
    k_ga<<<dim3(576), dim3(256), 0, stream>>>(Vt, Xga, Wb, W, bbar, Wc, 1);
    k_sv<<<dim3(32, 10), dim3(512), 0, stream>>>(Xb, Wc, Vt, outp, 1);
}